// Round 1
// baseline (72.299 us; speedup 1.0000x reference)
//
#include <hip/hip_runtime.h>
#include <hip/hip_bf16.h>
#include <math.h>

#define N_RAYS  32768
#define M_GAUSS 1024

typedef short v8s __attribute__((ext_vector_type(8)));
typedef float v4f __attribute__((ext_vector_type(4)));

__device__ __forceinline__ float fexp2(float x) {
#if __has_builtin(__builtin_amdgcn_exp2f)
    return __builtin_amdgcn_exp2f(x);
#else
    return exp2f(x);
#endif
}

union BFU { __hip_bfloat16 b; unsigned short u; };
__device__ __forceinline__ unsigned short f2bf(float f) { BFU x; x.b = __float2bfloat16(f); return x.u; }
__device__ __forceinline__ float bf2f(unsigned short u)  { BFU x; x.u = u; return __bfloat162float(x.b); }

// split f = hi + lo with hi,lo bf16; f - float(hi) is exact in fp32
__device__ __forceinline__ void split_bf16(float f, unsigned short& hi, unsigned short& lo) {
    hi = f2bf(f);
    lo = f2bf(f - bf2f(hi));
}

__device__ __forceinline__ void store8(unsigned short* dst, const unsigned short* s) {
    uint4 v;
    v.x = (unsigned)s[0] | ((unsigned)s[1] << 16);
    v.y = (unsigned)s[2] | ((unsigned)s[3] << 16);
    v.z = (unsigned)s[4] | ((unsigned)s[5] << 16);
    v.w = (unsigned)s[6] | ((unsigned)s[7] << 16);
    *reinterpret_cast<uint4*>(dst) = v;
}

// ---------------------------------------------------------------------------
// Prep (inversions only): fp32 adjugate inverse of each covariance, 15 coeffs
// with k=-0.5*log2(e) folded, split hi/lo into compact B tables:
//   B1c = w_hi  (decoder's (L&31) read replicates to k16-31 => w_hi*(f_hi+f_lo))
//   B2c = w_lo  (decoder pairs it with af2=[f_hi|0]       => w_lo*f_hi)
// Tile layout (per 16-gaussian tile t): uint4[32]: entry (quad*16 + col)
// holds B[k=quad*8..+7][n=col].
// Spread over 16 blocks x 64 threads for latency.
// ---------------------------------------------------------------------------
__global__ __launch_bounds__(64) void prep_kernel(
    const float*  __restrict__ means, // [M,4]
    const float*  __restrict__ covs,  // [M,4,4]
    unsigned short* __restrict__ Bt)  // 64 KB: B1c (32 KB) || B2c (32 KB)
{
    const int g = blockIdx.x * 64 + threadIdx.x;
    if (g >= M_GAUSS) return;

    const float4* C4 = reinterpret_cast<const float4*>(covs + 16 * g);
    const float4 r0 = C4[0], r1 = C4[1], r2 = C4[2], r3 = C4[3];
    const float a00=r0.x, a01=r0.y, a02=r0.z, a03=r0.w;
    const float a10=r1.x, a11=r1.y, a12=r1.z, a13=r1.w;
    const float a20=r2.x, a21=r2.y, a22=r2.z, a23=r2.w;
    const float a30=r3.x, a31=r3.y, a32=r3.z, a33=r3.w;

    const float s0=a00*a11-a01*a10, s1=a00*a12-a02*a10, s2=a00*a13-a03*a10;
    const float s3=a01*a12-a02*a11, s4=a01*a13-a03*a11, s5=a02*a13-a03*a12;
    const float c5=a22*a33-a23*a32, c4=a21*a33-a23*a31, c3=a21*a32-a22*a31;
    const float c2=a20*a33-a23*a30, c1=a20*a32-a22*a30, c0=a20*a31-a21*a30;
    const float det = s0*c5 - s1*c4 + s2*c3 + s3*c2 - s4*c1 + s5*c0;
    const float id  = 1.0f / det;

    const float b00=( a11*c5 - a12*c4 + a13*c3)*id;
    const float b01=(-a01*c5 + a02*c4 - a03*c3)*id;
    const float b10=(-a10*c5 + a12*c2 - a13*c1)*id;
    const float b11=( a00*c5 - a02*c2 + a03*c1)*id;
    const float b20=( a10*c4 - a11*c2 + a13*c0)*id;
    const float b21=(-a00*c4 + a01*c2 - a03*c0)*id;
    const float b30=(-a10*c3 + a11*c1 - a12*c0)*id;
    const float b31=( a00*c3 - a01*c1 + a02*c0)*id;
    const float b02=( a31*s5 - a32*s4 + a33*s3)*id;
    const float b03=(-a21*s5 + a22*s4 - a23*s3)*id;
    const float b12=(-a30*s5 + a32*s2 - a33*s1)*id;
    const float b13=( a20*s5 - a22*s2 + a23*s1)*id;
    const float b22=( a30*s4 - a31*s2 + a33*s0)*id;
    const float b23=(-a20*s4 + a21*s2 - a23*s0)*id;
    const float b32=(-a30*s3 + a31*s1 - a32*s0)*id;
    const float b33=( a20*s3 - a21*s1 + a22*s0)*id;

    const float m01=0.5f*(b01+b10), m02=0.5f*(b02+b20), m03=0.5f*(b03+b30);
    const float m12=0.5f*(b12+b21), m13=0.5f*(b13+b31), m23=0.5f*(b23+b32);

    const float4 mu = reinterpret_cast<const float4*>(means)[g];
    const float u0=mu.x, u1=mu.y, u2=mu.z, u3=mu.w;
    const float v0 = b00*u0 + m01*u1 + m02*u2 + m03*u3;
    const float v1 = m01*u0 + b11*u1 + m12*u2 + m13*u3;
    const float v2 = m02*u0 + m12*u1 + b22*u2 + m23*u3;
    const float v3 = m03*u0 + m13*u1 + m23*u2 + b33*u3;
    const float cc = u0*v0 + u1*v1 + u2*v2 + u3*v3;

    const float k  = -0.72134752044448170368f;   // -0.5 * log2(e)
    const float k2 = 2.0f * k;
    float w[16] = { k*b00,  k*b11,  k*b22,  k*b33,
                    k2*m01, k2*m02, k2*m03, k2*m12, k2*m13, k2*m23,
                    -k2*v0, -k2*v1, -k2*v2, -k2*v3, k*cc, 0.0f };
    unsigned short whi[16], wlo[16];
    #pragma unroll
    for (int q = 0; q < 16; ++q) split_bf16(w[q], whi[q], wlo[q]);

    const int t = g >> 4, cg = g & 15;
    unsigned short* b1 = Bt + (size_t)t * 32 * 8;                     // B1c
    store8(b1 + (0*16 + cg) * 8, whi + 0);   // quad 0: w_hi k0-7
    store8(b1 + (1*16 + cg) * 8, whi + 8);   // quad 1: w_hi k8-15
    unsigned short* b2 = Bt + (size_t)2048 * 8 + (size_t)t * 32 * 8;  // B2c
    store8(b2 + (0*16 + cg) * 8, wlo + 0);
    store8(b2 + (1*16 + cg) * 8, wlo + 8);
}

// ---------------------------------------------------------------------------
// Decoder R7: wave-independent structure.
//   - 512 blocks x 512 threads (8 waves). Block owns 64 rays.
//   - Wave w: row-tile rt = w&3 (16 rays), m-half h = w>>2 (tiles h*32..+32).
//   - A-fragment built IN REGISTERS per wave (no LDS, no barrier).
//   - B fragments read DIRECTLY from global (L2-hot 64 KB, zero intra-block
//     reuse made LDS staging pure critical-path overhead).
//   - af2 = [f_hi | 0] makes mfma(af2, [w_lo|w_lo]) == old masked [w_lo|0]
//     product with zero per-iteration VALU masking.
//   - Column reduce via 16-lane shfl_xor butterfly; ONE barrier total to
//     combine the two m-halves through 512 B of LDS.
// ---------------------------------------------------------------------------
__global__ __launch_bounds__(512, 4) void decoder_kernel(
    const float2* __restrict__ org,    // [N]
    const float2* __restrict__ dir,    // [N]
    const uint4* __restrict__ Btg,     // 64 KB B tables (B1c || B2c)
    const float* __restrict__ labels,  // [M]
    float*       __restrict__ out)     // [N]
{
    __shared__ float P[2 * 64];        // per-half partial ray sums

    const int tid = threadIdx.x;
    const int L   = tid & 63;
    const int w   = tid >> 6;
    const int c15 = L & 15;
    const int q   = L >> 4;
    const int rt  = w & 3;             // row-tile (16 rays) of this wave
    const int h   = w >> 2;            // m-half: tiles [h*32, h*32+32)

    // ---- per-wave A fragments, built in registers ----
    // MFMA A layout: lane L holds row m = L&15, k = q*8 + j.
    // Effective A columns: k0-15 = f_hi, k16-31 = f_lo.
    const int ray = blockIdx.x * 64 + rt * 16 + c15;
    const float2 o = org[ray];
    const float2 d = dir[ray];
    const float p0 = o.x, p1 = o.y, p2 = d.x, p3 = d.y;

    const float f0 = p0*p0, f1 = p1*p1, f2 = p2*p2, f3 = p3*p3;
    const float f4 = p0*p1, f5 = p0*p2, f6 = p0*p3, f7 = p1*p2;
    const float f8 = p1*p3, f9 = p2*p3, f10 = p0,  f11 = p1;
    const float f12 = p2,  f13 = p3,  f14 = 1.0f,  f15 = 0.0f;

    const bool k8  = (q & 1) != 0;     // lane's k-block covers f[8..15]
    const bool loQ = (q >> 1) != 0;    // lane's k-block is the f_lo half

    float g[8];
    g[0] = k8 ? f8  : f0;
    g[1] = k8 ? f9  : f1;
    g[2] = k8 ? f10 : f2;
    g[3] = k8 ? f11 : f3;
    g[4] = k8 ? f12 : f4;
    g[5] = k8 ? f13 : f5;
    g[6] = k8 ? f14 : f6;
    g[7] = k8 ? f15 : f7;

    unsigned short va[8], va2[8];
    #pragma unroll
    for (int j = 0; j < 8; ++j) {
        unsigned short hi, lo;
        split_bf16(g[j], hi, lo);
        va[j]  = loQ ? lo : hi;                    // af  = [f_hi | f_lo]
        va2[j] = loQ ? (unsigned short)0 : hi;     // af2 = [f_hi |  0  ]
    }
    union { uint4 u; v8s s; } afu, af2u;
    afu.u.x  = (unsigned)va[0]  | ((unsigned)va[1]  << 16);
    afu.u.y  = (unsigned)va[2]  | ((unsigned)va[3]  << 16);
    afu.u.z  = (unsigned)va[4]  | ((unsigned)va[5]  << 16);
    afu.u.w  = (unsigned)va[6]  | ((unsigned)va[7]  << 16);
    af2u.u.x = (unsigned)va2[0] | ((unsigned)va2[1] << 16);
    af2u.u.y = (unsigned)va2[2] | ((unsigned)va2[3] << 16);
    af2u.u.z = (unsigned)va2[4] | ((unsigned)va2[5] << 16);
    af2u.u.w = (unsigned)va2[6] | ((unsigned)va2[7] << 16);
    const v8s af  = afu.s;
    const v8s af2 = af2u.s;

    // ---- main loop: 32 m-tiles, B direct from global (L2-hot) ----
    const uint4* B1 = Btg;             // 2048 uint4 (32 KB)
    const uint4* B2 = Btg + 2048;      // 2048 uint4 (32 KB)
    const int l31 = L & 31;

    v4f acc = (v4f){0.f, 0.f, 0.f, 0.f};
    #pragma unroll 8
    for (int i = 0; i < 32; ++i) {
        const int t = h * 32 + i;
        union { uint4 u; v8s s; } b1x, b2x;
        b1x.u = B1[t * 32 + l31];                 // [w_hi | w_hi]
        b2x.u = B2[t * 32 + l31];                 // [w_lo | w_lo]
        const float lab = labels[t * 16 + c15];

        v4f s = __builtin_amdgcn_mfma_f32_16x16x32_bf16(
                    af2, b2x.s, (v4f){0.f, 0.f, 0.f, 0.f}, 0, 0, 0);
        s = __builtin_amdgcn_mfma_f32_16x16x32_bf16(af, b1x.s, s, 0, 0, 0);

        #pragma unroll
        for (int r = 0; r < 4; ++r)
            acc[r] = fmaf(lab, fexp2(s[r]), acc[r]);
    }

    // ---- column reduce: sum over the 16 gaussian-cols (lanes of the group).
    // D layout: col = L&15, row(ray) = q*4 + r.
    float s0 = acc[0], s1 = acc[1], s2 = acc[2], s3 = acc[3];
    #pragma unroll
    for (int m = 1; m < 16; m <<= 1) {
        s0 += __shfl_xor(s0, m);
        s1 += __shfl_xor(s1, m);
        s2 += __shfl_xor(s2, m);
        s3 += __shfl_xor(s3, m);
    }
    float val = s0;
    val = (c15 == 1) ? s1 : val;
    val = (c15 == 2) ? s2 : val;
    val = (c15 == 3) ? s3 : val;
    if (c15 < 4) P[h * 64 + rt * 16 + q * 4 + c15] = val;

    __syncthreads();

    // ---- combine the two m-halves, sigmoid, store ----
    if (tid < 64) {
        const float ts = P[tid] + P[64 + tid];
        const float e = fexp2(-ts * 1.4426950408889634f);
        out[blockIdx.x * 64 + tid] = 1.0f / (1.0f + e);
    }
}

extern "C" void kernel_launch(void* const* d_in, const int* in_sizes, int n_in,
                              void* d_out, int out_size, void* d_ws, size_t ws_size,
                              hipStream_t stream) {
    const float* origins    = (const float*)d_in[0];  // [N,2]
    const float* directions = (const float*)d_in[1];  // [N,2]
    const float* means      = (const float*)d_in[2];  // [M,4]
    const float* covs       = (const float*)d_in[3];  // [M,4,4]
    const float* labels     = (const float*)d_in[4];  // [M]
    float* out = (float*)d_out;

    unsigned short* Bt = (unsigned short*)d_ws;       // 64 KB compact B tables

    prep_kernel<<<dim3(M_GAUSS / 64), dim3(64), 0, stream>>>(means, covs, Bt);
    decoder_kernel<<<dim3(N_RAYS / 64), dim3(512), 0, stream>>>(
        (const float2*)origins, (const float2*)directions,
        (const uint4*)Bt, labels, out);
}